// Round 9
// baseline (68.247 us; speedup 1.0000x reference)
//
#include <hip/hip_runtime.h>
#include <hip/hip_bf16.h>

// RBF Gram matrix: out[i][j] = exp(-||X_i - Y_j||^2), X,Y fp32 [8192][256].
// prep_nl: X,Y -> fp8 e4m3 panels in MFMA-native fragment order + fp32 norms.
//   Native layout: byte addr = (row/64)*16384 + ((row%64)/16)*4096 + (k/32)*512
//                              + ((k%32)/8)*16*8 + (row%16)*8 + k%8
//   i.e. [rb][m][s][lane=kh*16+fr][8B] -- a wave's frag load is 512B contiguous.
// gemm_nl: ZERO LDS. 128x128 tile, 4 waves, frags loaded straight from L2
//   (global_load_dwordx2, coalesced), register double-buffer over 8 K-steps,
//   fp8 MFMA 16x16x32, per-XCD super-block traversal, fused exp + plain stores.

#define MROWS 8192
#define NDIM  256
#define BM 128
#define BN 128

typedef float f32x4 __attribute__((ext_vector_type(4)));

// fp32 -> OCP e4m3fn, RNE, saturating (no NaN inputs expected)
__device__ inline unsigned char f2e4m3(float f) {
    unsigned u = __float_as_uint(f);
    unsigned s = (u >> 24) & 0x80u;
    unsigned au = u & 0x7fffffffu;
    float a = __uint_as_float(au);
    if (a >= 448.0f) return (unsigned char)(s | 0x7E);
    if (a < 0.015625f) {                       // below normal min 2^-6
        float q = a * 512.0f;                  // grid of 2^-9
        int m = (int)rintf(q);                 // 0..8
        return (unsigned char)(s | (unsigned)m);  // m==8 -> 0x08 == 2^-6 normal
    }
    unsigned r = au + 0x7FFFFu + ((au >> 20) & 1u);   // RNE drop 20 bits
    int e = (int)(r >> 23) - 127;              // -6..8 after rounding
    unsigned m3 = (r >> 20) & 7u;
    return (unsigned char)(s | ((unsigned)(e + 7) << 3) | m3);
}

// ---------- prep: fp8 convert into native layout + fp32 norms ----------
// 1024 groups of 16 rows (512 X + 512 Y); one wave per group.
__global__ __launch_bounds__(256) void rbf_prep_nl(const float* __restrict__ X,
                                                   const float* __restrict__ Y,
                                                   unsigned char* __restrict__ Xn,
                                                   unsigned char* __restrict__ Yn,
                                                   float* __restrict__ x2,
                                                   float* __restrict__ y2) {
    const int w    = threadIdx.x >> 6;
    const int lane = threadIdx.x & 63;
    const int grp  = blockIdx.x * 4 + w;       // 0..1023
    const float* src;
    unsigned char* dstb;
    float* dstn;
    int g;
    if (grp < 512) { src = X; dstb = Xn; dstn = x2; g = grp; }
    else           { src = Y; dstb = Yn; dstn = y2; g = grp - 512; }

    const int fr = lane & 15;
    const int kh = lane >> 4;
    const float* rowp = src + (size_t)(g * 16 + fr) * NDIM;
    unsigned char* nat = dstb + (size_t)(g >> 2) * 16384 + (size_t)(g & 3) * 4096;

    float ssum = 0.0f;
#pragma unroll
    for (int j = 0; j < 8; ++j) {
        // lane converts f32 k in [32j+8kh, 32j+8kh+8) of row fr
        f32x4 a = *(const f32x4*)(rowp + 32 * j + 8 * kh);
        f32x4 b = *(const f32x4*)(rowp + 32 * j + 8 * kh + 4);
        unsigned long long pk = 0;
        pk |= (unsigned long long)f2e4m3(a[0]);
        pk |= (unsigned long long)f2e4m3(a[1]) << 8;
        pk |= (unsigned long long)f2e4m3(a[2]) << 16;
        pk |= (unsigned long long)f2e4m3(a[3]) << 24;
        pk |= (unsigned long long)f2e4m3(b[0]) << 32;
        pk |= (unsigned long long)f2e4m3(b[1]) << 40;
        pk |= (unsigned long long)f2e4m3(b[2]) << 48;
        pk |= (unsigned long long)f2e4m3(b[3]) << 56;
        *(unsigned long long*)(nat + j * 512 + lane * 8) = pk;   // 512B/wave coalesced
        ssum += a[0]*a[0] + a[1]*a[1] + a[2]*a[2] + a[3]*a[3]
              + b[0]*b[0] + b[1]*b[1] + b[2]*b[2] + b[3]*b[3];
    }
    // row fr's partials live in lanes fr, fr+16, fr+32, fr+48 -> fold kh
    ssum += __shfl_xor(ssum, 16);
    ssum += __shfl_xor(ssum, 32);
    if (lane < 16) dstn[g * 16 + lane] = ssum;
}

// ---------- 128x128 fp8 GEMM + fused exp, ZERO LDS ----------
__global__ __launch_bounds__(256, 4) void rbf_gemm_nl(
        const unsigned char* __restrict__ Xn,
        const unsigned char* __restrict__ Yn,
        const float* __restrict__ x2,
        const float* __restrict__ y2,
        float* __restrict__ out) {
    const int tid  = threadIdx.x;
    const int lane = tid & 63;
    const int wid  = tid >> 6;     // 0..3
    const int wy   = wid >> 1;
    const int wx   = wid & 1;
    const int fr   = lane & 15;
    const int kh   = lane >> 4;    // 0..3

    // per-XCD 8x8 super-block traversal (bijective over 4096 blocks)
    const int bid  = blockIdx.x;
    const int xcd  = bid & 7;
    const int idx  = bid >> 3;          // 0..511
    const int sb   = idx >> 6;          // col-group 0..7
    const int r8   = (idx >> 3) & 7;
    const int c8   = idx & 7;
    const int row0 = (xcd * 8 + r8) * BM;
    const int col0 = (sb * 8 + c8) * BN;

    // native-layout bases for this wave's 64x256 A panel and 64x256 B panel
    const unsigned char* Abase = Xn + ((size_t)(row0 >> 6) + wy) * 16384 + lane * 8;
    const unsigned char* Bbase = Yn + ((size_t)(col0 >> 6) + wx) * 16384 + lane * 8;

    f32x4 acc[4][4] = {};
    long af[2][4], bf[2][4];

#define LDFRAG(buf, s)                                                        \
    {                                                                         \
        _Pragma("unroll")                                                     \
        for (int m = 0; m < 4; ++m)                                           \
            af[buf][m] = *(const long*)(Abase + m * 4096 + (s) * 512);        \
        _Pragma("unroll")                                                     \
        for (int n = 0; n < 4; ++n)                                           \
            bf[buf][n] = *(const long*)(Bbase + n * 4096 + (s) * 512);        \
    }

    LDFRAG(0, 0)
#pragma unroll
    for (int s = 0; s < 8; ++s) {
        const int cur = s & 1;
        const int nxt = cur ^ 1;
        if (s < 7) LDFRAG(nxt, s + 1)
        __builtin_amdgcn_s_setprio(1);
#pragma unroll
        for (int m = 0; m < 4; ++m)
#pragma unroll
            for (int n = 0; n < 4; ++n)
                acc[m][n] = __builtin_amdgcn_mfma_f32_16x16x32_fp8_fp8(
                    af[cur][m], bf[cur][n], acc[m][n], 0, 0, 0);
        __builtin_amdgcn_s_setprio(0);
    }
#undef LDFRAG

    // ---- epilogue: exp(-(x2 + y2 - 2*xy)), plain direct stores ----
    // C/D frag: col = lane&15 (+16n), row = kh*4 + reg (+16m).
    const int ci = row0 + wy * 64;
    const int cj = col0 + wx * 64 + fr;
    float yv[4];
#pragma unroll
    for (int n = 0; n < 4; ++n) yv[n] = y2[cj + n * 16];
#pragma unroll
    for (int m = 0; m < 4; ++m) {
#pragma unroll
        for (int rg = 0; rg < 4; ++rg) {
            const int i  = ci + m * 16 + kh * 4 + rg;
            const float xi = x2[i];
            float* orow = out + (size_t)i * MROWS + cj;
#pragma unroll
            for (int n = 0; n < 4; ++n) {
                float sq = fmaxf(xi + yv[n] - 2.0f * acc[m][n][rg], 0.0f);
                orow[n * 16] = __expf(-sq);
            }
        }
    }
}

extern "C" void kernel_launch(void* const* d_in, const int* in_sizes, int n_in,
                              void* d_out, int out_size, void* d_ws, size_t ws_size,
                              hipStream_t stream) {
    const float* X = (const float*)d_in[0];
    const float* Y = (const float*)d_in[1];
    float* out = (float*)d_out;

    unsigned char* Xn = (unsigned char*)d_ws;                 // 2 MiB native fp8
    unsigned char* Yn = Xn + (size_t)MROWS * NDIM;            // 2 MiB
    float* x2 = (float*)(Yn + (size_t)MROWS * NDIM);
    float* y2 = x2 + MROWS;

    rbf_prep_nl<<<256, 256, 0, stream>>>(X, Y, Xn, Yn, x2, y2);

    rbf_gemm_nl<<<(MROWS / BM) * (MROWS / BN), 256, 0, stream>>>(Xn, Yn, x2, y2, out);
}

// Round 11
// 58.317 us; speedup vs baseline: 1.1703x; 1.1703x over previous
//
#include <hip/hip_runtime.h>
#include <hip/hip_bf16.h>

// RBF Gram matrix: out[i][j] = exp(-||X_i - Y_j||^2), X,Y fp32 [8192][256].
// prep: X,Y -> fp8 e4m3 panels (RNE) + fp32 norms.
// gemm128: R6 structure (best: 58.1us) + column-permuted B staging so each
//   lane's 4 accumulators are contiguous output columns -> float4 stores.
//   128x128 tile, 4 waves, BK=128 fp8, 32KiB single-buffer LDS, 4 blocks/CU;
//   global_load_lds w=16 (pre-swizzled source); per-XCD 8x8 super-block
//   traversal; fp8 MFMA 16x16x32; fused exp epilogue, dwordx4 stores.
// (Resubmission of round-10 kernel: bench infra failed, no data.)

#define MROWS 8192
#define NDIM  256
#define BM 128
#define BN 128
#define BK 128
#define NT (NDIM / BK)   // 2

typedef float f32x4 __attribute__((ext_vector_type(4)));

typedef __attribute__((address_space(1))) const unsigned char gu8;
typedef __attribute__((address_space(3))) unsigned char lu8;

// fp32 -> OCP e4m3fn, RNE, saturating (no NaN inputs expected)
__device__ inline unsigned char f2e4m3(float f) {
    unsigned u = __float_as_uint(f);
    unsigned s = (u >> 24) & 0x80u;
    unsigned au = u & 0x7fffffffu;
    float a = __uint_as_float(au);
    if (a >= 448.0f) return (unsigned char)(s | 0x7E);
    if (a < 0.015625f) {                       // below normal min 2^-6
        float q = a * 512.0f;                  // grid of 2^-9
        int m = (int)rintf(q);                 // 0..8
        return (unsigned char)(s | (unsigned)m);  // m==8 -> 0x08 == 2^-6 normal
    }
    unsigned r = au + 0x7FFFFu + ((au >> 20) & 1u);   // RNE drop 20 bits
    int e = (int)(r >> 23) - 127;              // -6..8 after rounding
    unsigned m3 = (r >> 20) & 7u;
    return (unsigned char)(s | ((unsigned)(e + 7) << 3) | m3);
}

// ---------- prep: fp8 convert + fp32 norms, one wave per row ----------
__global__ __launch_bounds__(256) void rbf_prep(const float* __restrict__ X,
                                                const float* __restrict__ Y,
                                                unsigned char* __restrict__ Xb,
                                                unsigned char* __restrict__ Yb,
                                                float* __restrict__ x2,
                                                float* __restrict__ y2) {
    const int gw   = (blockIdx.x * blockDim.x + threadIdx.x) >> 6;  // 0..16383
    const int lane = threadIdx.x & 63;
    const float* src;
    unsigned char* dstb;
    float* dstn;
    int row;
    if (gw < MROWS) { src = X; dstb = Xb; dstn = x2; row = gw; }
    else            { src = Y; dstb = Yb; dstn = y2; row = gw - MROWS; }

    f32x4 v = *(const f32x4*)(src + (size_t)row * NDIM + lane * 4);
    uchar4 q;
    q.x = f2e4m3(v[0]); q.y = f2e4m3(v[1]); q.z = f2e4m3(v[2]); q.w = f2e4m3(v[3]);
    *(uchar4*)(dstb + (size_t)row * NDIM + lane * 4) = q;

    float ssum = v[0]*v[0] + v[1]*v[1] + v[2]*v[2] + v[3]*v[3];
#pragma unroll
    for (int off = 32; off > 0; off >>= 1) ssum += __shfl_xor(ssum, off);
    if (lane == 0) dstn[row] = ssum;
}

// ---------- 128x128 fp8 GEMM + fused exp, 4 blocks/CU ----------
__global__ __launch_bounds__(256, 4) void rbf_gemm128(
        const unsigned char* __restrict__ Xb,
        const unsigned char* __restrict__ Yb,
        const float* __restrict__ x2,
        const float* __restrict__ y2,
        float* __restrict__ out) {
    __shared__ __align__(16) unsigned char lds[2 * BM * BK];  // 32 KiB: A | B

    const int tid   = threadIdx.x;
    const int lane  = tid & 63;
    const int wid   = tid >> 6;     // 0..3
    const int wy    = wid >> 1;
    const int wx    = wid & 1;
    const int fr    = lane & 15;
    const int kh    = lane >> 4;    // 0..3 (k-group)

    // per-XCD 8x8 super-block traversal (bijective over 4096 blocks)
    const int bid  = blockIdx.x;
    const int xcd  = bid & 7;
    const int idx  = bid >> 3;          // 0..511
    const int sb   = idx >> 6;          // col-group 0..7
    const int r8   = (idx >> 3) & 7;
    const int c8   = idx & 7;
    const int row0 = (xcd * 8 + r8) * BM;
    const int col0 = (sb * 8 + c8) * BN;

    // staging: per matrix 16KB = 1024 x 16B chunks; 8 chunks per 128B row.
    const int rr  = tid >> 3;                 // 0..31
    const int cc  = tid & 7;
    const int sch = (cc ^ (rr & 7)) << 4;     // pre-swizzled byte offset in row

    f32x4 acc[4][4] = {};

    for (int t = 0; t < NT; ++t) {
        const int k0 = t * BK;
#pragma unroll
        for (int p = 0; p < 4; ++p) {
            const int r = p * 32 + rr;
            // B column-permute: LDS row r holds Y row perm(r) so that a lane's
            // 4 B-frag slots map to 4 CONTIGUOUS output columns.
            //   perm(r) = (r&64) | ((r&15)*4 + ((r>>4)&3))
            const int pr = (r & 64) | (((r & 15) << 2) | ((r >> 4) & 3));
            const unsigned char* sA = Xb + (size_t)(row0 + r)  * NDIM + k0 + sch;
            const unsigned char* sB = Yb + (size_t)(col0 + pr) * NDIM + k0 + sch;
            unsigned char* lA = lds + (p * 256 + wid * 64) * 16;  // wave-uniform base
            unsigned char* lB = lA + BM * BK;
            __builtin_amdgcn_global_load_lds((gu8*)sA, (lu8*)lA, 16, 0, 0);
            __builtin_amdgcn_global_load_lds((gu8*)sB, (lu8*)lB, 16, 0, 0);
        }
        asm volatile("s_waitcnt vmcnt(0)" ::: "memory");
        __builtin_amdgcn_s_barrier();
        asm volatile("" ::: "memory");

        const unsigned char* A = lds;
        const unsigned char* B = lds + BM * BK;
        const int j2 = kh >> 1;             // chunk sub-index from kh
        const int h8 = (kh & 1) * 8;        // 8B half within chunk
#pragma unroll
        for (int s = 0; s < 4; ++s) {       // K=32 step within BK=128
            long bfv[4];
#pragma unroll
            for (int n = 0; n < 4; ++n) {
                const int r  = wx * 64 + n * 16 + fr;
                const int ch = (2 * s + j2) ^ (r & 7);
                bfv[n] = *(const long*)(B + r * BK + ch * 16 + h8);
            }
            __builtin_amdgcn_s_setprio(1);
#pragma unroll
            for (int m = 0; m < 4; ++m) {
                const int r  = wy * 64 + m * 16 + fr;
                const int ch = (2 * s + j2) ^ (r & 7);
                long af = *(const long*)(A + r * BK + ch * 16 + h8);
#pragma unroll
                for (int n = 0; n < 4; ++n)
                    acc[m][n] = __builtin_amdgcn_mfma_f32_16x16x32_fp8_fp8(
                        af, bfv[n], acc[m][n], 0, 0, 0);
            }
            __builtin_amdgcn_s_setprio(0);
        }
        if (t < NT - 1) {
            asm volatile("" ::: "memory");
            __builtin_amdgcn_s_barrier();   // LDS free for next stage
        }
    }

    // ---- epilogue: exp(-(x2 + y2 - 2*xy)), float4 stores ----
    // With B-permute: acc[m][n] -> col = col0 + wx*64 + 4*fr + n (contiguous!)
    // C/D frag rows: i = row0 + wy*64 + m*16 + kh*4 + rg.
    const int ci = row0 + wy * 64;
    const int cj = col0 + wx * 64 + fr * 4;
    const f32x4 yv = *(const f32x4*)(y2 + cj);
#pragma unroll
    for (int m = 0; m < 4; ++m) {
#pragma unroll
        for (int rg = 0; rg < 4; ++rg) {
            const int i  = ci + m * 16 + kh * 4 + rg;
            const float xi = x2[i];
            f32x4 v;
#pragma unroll
            for (int n = 0; n < 4; ++n) {
                float sq = fmaxf(xi + yv[n] - 2.0f * acc[m][n][rg], 0.0f);
                v[n] = __expf(-sq);
            }
            *(f32x4*)(out + (size_t)i * MROWS + cj) = v;
        }
    }
}

extern "C" void kernel_launch(void* const* d_in, const int* in_sizes, int n_in,
                              void* d_out, int out_size, void* d_ws, size_t ws_size,
                              hipStream_t stream) {
    const float* X = (const float*)d_in[0];
    const float* Y = (const float*)d_in[1];
    float* out = (float*)d_out;

    unsigned char* Xb = (unsigned char*)d_ws;                 // 2 MiB
    unsigned char* Yb = Xb + (size_t)MROWS * NDIM;            // 2 MiB
    float* x2 = (float*)(Yb + (size_t)MROWS * NDIM);
    float* y2 = x2 + MROWS;

    rbf_prep<<<(2 * MROWS) / 4, 256, 0, stream>>>(X, Y, Xb, Yb, x2, y2);

    rbf_gemm128<<<(MROWS / BM) * (MROWS / BN), 256, 0, stream>>>(Xb, Yb, x2, y2, out);
}

// Round 12
// 57.611 us; speedup vs baseline: 1.1846x; 1.0123x over previous
//
#include <hip/hip_runtime.h>
#include <hip/hip_bf16.h>

// RBF Gram matrix: out[i][j] = exp(-||X_i - Y_j||^2), X,Y fp32 [8192][256].
// prep: X,Y -> fp8 e4m3 panels (RNE) + fp32 norms.
// gemm128: 128x128 tile, 4 waves, fp8 MFMA 16x16x32, 4 blocks/CU.
//   NEW (R12): BK=64 with A|B interleaved per 128B LDS row -> 16KB/buffer,
//   DOUBLE-buffered (32KB total, occupancy kept) with counted vmcnt(4) so
//   next-tile staging stays in flight under compute (T3/T4-minimal).
//   Keeps: global_load_lds w=16 pre-swizzled source, per-XCD 8x8 super-block
//   traversal, B column-permute -> float4 epilogue stores, fused exp.

#define MROWS 8192
#define NDIM  256
#define BM 128
#define BN 128
#define BK 64
#define NT (NDIM / BK)   // 4

typedef float f32x4 __attribute__((ext_vector_type(4)));

typedef __attribute__((address_space(1))) const unsigned char gu8;
typedef __attribute__((address_space(3))) unsigned char lu8;

// fp32 -> OCP e4m3fn, RNE, saturating (no NaN inputs expected)
__device__ inline unsigned char f2e4m3(float f) {
    unsigned u = __float_as_uint(f);
    unsigned s = (u >> 24) & 0x80u;
    unsigned au = u & 0x7fffffffu;
    float a = __uint_as_float(au);
    if (a >= 448.0f) return (unsigned char)(s | 0x7E);
    if (a < 0.015625f) {                       // below normal min 2^-6
        float q = a * 512.0f;                  // grid of 2^-9
        int m = (int)rintf(q);                 // 0..8
        return (unsigned char)(s | (unsigned)m);  // m==8 -> 0x08 == 2^-6 normal
    }
    unsigned r = au + 0x7FFFFu + ((au >> 20) & 1u);   // RNE drop 20 bits
    int e = (int)(r >> 23) - 127;              // -6..8 after rounding
    unsigned m3 = (r >> 20) & 7u;
    return (unsigned char)(s | ((unsigned)(e + 7) << 3) | m3);
}

// ---------- prep: fp8 convert + fp32 norms, one wave per row ----------
__global__ __launch_bounds__(256) void rbf_prep(const float* __restrict__ X,
                                                const float* __restrict__ Y,
                                                unsigned char* __restrict__ Xb,
                                                unsigned char* __restrict__ Yb,
                                                float* __restrict__ x2,
                                                float* __restrict__ y2) {
    const int gw   = (blockIdx.x * blockDim.x + threadIdx.x) >> 6;  // 0..16383
    const int lane = threadIdx.x & 63;
    const float* src;
    unsigned char* dstb;
    float* dstn;
    int row;
    if (gw < MROWS) { src = X; dstb = Xb; dstn = x2; row = gw; }
    else            { src = Y; dstb = Yb; dstn = y2; row = gw - MROWS; }

    f32x4 v = *(const f32x4*)(src + (size_t)row * NDIM + lane * 4);
    uchar4 q;
    q.x = f2e4m3(v[0]); q.y = f2e4m3(v[1]); q.z = f2e4m3(v[2]); q.w = f2e4m3(v[3]);
    *(uchar4*)(dstb + (size_t)row * NDIM + lane * 4) = q;

    float ssum = v[0]*v[0] + v[1]*v[1] + v[2]*v[2] + v[3]*v[3];
#pragma unroll
    for (int off = 32; off > 0; off >>= 1) ssum += __shfl_xor(ssum, off);
    if (lane == 0) dstn[row] = ssum;
}

// ---------- 128x128 fp8 GEMM + fused exp, 4 blocks/CU, dbuf BK=64 ----------
__global__ __launch_bounds__(256, 4) void rbf_gemm128(
        const unsigned char* __restrict__ Xb,
        const unsigned char* __restrict__ Yb,
        const float* __restrict__ x2,
        const float* __restrict__ y2,
        float* __restrict__ out) {
    // Each 128B LDS row r = [A row r (64B) | B row r (64B)], XOR-(r&7) chunk
    // swizzle across the full 8-chunk row (proven conflict-free geometry).
    __shared__ __align__(16) unsigned char lds[2][BM * 128];  // 2 x 16 KiB

    const int tid  = threadIdx.x;
    const int lane = tid & 63;
    const int wid  = tid >> 6;     // 0..3
    const int wy   = wid >> 1;
    const int wx   = wid & 1;
    const int fr   = lane & 15;
    const int kh   = lane >> 4;    // 0..3 (k-group)

    // per-XCD 8x8 super-block traversal (bijective over 4096 blocks)
    const int bid  = blockIdx.x;
    const int xcd  = bid & 7;
    const int idx  = bid >> 3;          // 0..511
    const int sb   = idx >> 6;          // col-group 0..7
    const int r8   = (idx >> 3) & 7;
    const int c8   = idx & 7;
    const int row0 = (xcd * 8 + r8) * BM;
    const int col0 = (sb * 8 + c8) * BN;

    // staging: 1024 chunks of 16B per tile; thread handles chunks p*256+tid.
    // r = p*32 + (tid>>3), c = tid&7; swizzled chunk sw = c ^ (r&7):
    //   sw<4 -> A row r k-chunk sw;  sw>=4 -> B row pr(r) k-chunk sw-4.
    const int rr = tid >> 3;                 // 0..31
    const int cc = tid & 7;
    const int sw = cc ^ (rr & 7);
    const unsigned char* srcp[4];
#pragma unroll
    for (int p = 0; p < 4; ++p) {
        const int r = p * 32 + rr;
        if (sw < 4) {
            srcp[p] = Xb + (size_t)(row0 + r) * NDIM + sw * 16;
        } else {
            // B column-permute: LDS B-row r holds Y row pr(r) so a lane's
            // 4 B-frag slots are 4 contiguous output columns.
            const int pr = (r & 64) | ((r & 15) << 2) | ((r >> 4) & 3);
            srcp[p] = Yb + (size_t)(col0 + pr) * NDIM + (sw - 4) * 16;
        }
    }

    f32x4 acc[4][4] = {};

    // prologue: stage tile 0 into buf 0 (4 loads/thread outstanding)
#pragma unroll
    for (int p = 0; p < 4; ++p)
        __builtin_amdgcn_global_load_lds((gu8*)(srcp[p]),
                                         (lu8*)&lds[0][(p * 256 + wid * 64) * 16],
                                         16, 0, 0);

    for (int t = 0; t < NT; ++t) {
        if (t < NT - 1) {
            const int k0 = (t + 1) * BK;
#pragma unroll
            for (int p = 0; p < 4; ++p)
                __builtin_amdgcn_global_load_lds((gu8*)(srcp[p] + k0),
                                                 (lu8*)&lds[(t + 1) & 1][(p * 256 + wid * 64) * 16],
                                                 16, 0, 0);
            asm volatile("s_waitcnt vmcnt(4)" ::: "memory");  // tile t landed; t+1 in flight
        } else {
            asm volatile("s_waitcnt vmcnt(0)" ::: "memory");
        }
        __builtin_amdgcn_s_barrier();
        asm volatile("" ::: "memory");

        const unsigned char* buf = lds[t & 1];
#pragma unroll
        for (int s = 0; s < 2; ++s) {       // two K=32 steps in BK=64
            long bfv[4];
#pragma unroll
            for (int n = 0; n < 4; ++n) {
                const int r  = wx * 64 + n * 16 + fr;
                const int ch = (4 + 2 * s + (kh >> 1)) ^ (r & 7);   // B half
                bfv[n] = *(const long*)(buf + r * 128 + ch * 16 + (kh & 1) * 8);
            }
            __builtin_amdgcn_s_setprio(1);
#pragma unroll
            for (int m = 0; m < 4; ++m) {
                const int r  = wy * 64 + m * 16 + fr;
                const int ch = (2 * s + (kh >> 1)) ^ (r & 7);       // A half
                long af = *(const long*)(buf + r * 128 + ch * 16 + (kh & 1) * 8);
#pragma unroll
                for (int n = 0; n < 4; ++n)
                    acc[m][n] = __builtin_amdgcn_mfma_f32_16x16x32_fp8_fp8(
                        af, bfv[n], acc[m][n], 0, 0, 0);
            }
            __builtin_amdgcn_s_setprio(0);
        }
        if (t < NT - 1) {
            asm volatile("" ::: "memory");
            __builtin_amdgcn_s_barrier();   // all reads of buf done before t+2 stage
        }
    }

    // ---- epilogue: exp(-(x2 + y2 - 2*xy)), float4 stores ----
    // With B-permute: acc[m][n] -> col = col0 + wx*64 + 4*fr + n (contiguous).
    // C/D frag rows: i = row0 + wy*64 + m*16 + kh*4 + rg.
    const int ci = row0 + wy * 64;
    const int cj = col0 + wx * 64 + fr * 4;
    const f32x4 yv = *(const f32x4*)(y2 + cj);
#pragma unroll
    for (int m = 0; m < 4; ++m) {
#pragma unroll
        for (int rg = 0; rg < 4; ++rg) {
            const int i  = ci + m * 16 + kh * 4 + rg;
            const float xi = x2[i];
            f32x4 v;
#pragma unroll
            for (int n = 0; n < 4; ++n) {
                float sq = fmaxf(xi + yv[n] - 2.0f * acc[m][n][rg], 0.0f);
                v[n] = __expf(-sq);
            }
            *(f32x4*)(out + (size_t)i * MROWS + cj) = v;
        }
    }
}

extern "C" void kernel_launch(void* const* d_in, const int* in_sizes, int n_in,
                              void* d_out, int out_size, void* d_ws, size_t ws_size,
                              hipStream_t stream) {
    const float* X = (const float*)d_in[0];
    const float* Y = (const float*)d_in[1];
    float* out = (float*)d_out;

    unsigned char* Xb = (unsigned char*)d_ws;                 // 2 MiB
    unsigned char* Yb = Xb + (size_t)MROWS * NDIM;            // 2 MiB
    float* x2 = (float*)(Yb + (size_t)MROWS * NDIM);
    float* y2 = x2 + MROWS;

    rbf_prep<<<(2 * MROWS) / 4, 256, 0, stream>>>(X, Y, Xb, Yb, x2, y2);

    rbf_gemm128<<<(MROWS / BM) * (MROWS / BN), 256, 0, stream>>>(Xb, Yb, x2, y2, out);
}